// Round 1
// baseline (8832.730 us; speedup 1.0000x reference)
//
#include <hip/hip_runtime.h>
#include <math.h>

// ---------------- workspace layout (bytes) ----------------
// y3 [8,128,64,64]   f32 @ 0          (16,777,216)
// y1 [8,32,256,256]  f32 @ 16777216   (67,108,864)
// y2 [8,64,128,128]  f32 @ 83886080   (33,554,432)
// y4 [8,256,128,128] f32 @ 16777216   (134,217,728)  -- reuses y1+y2 (dead by then)
// ms (mean,rstd) 2048 float2 @ 150994944 (16,384)
// lab [8,128,128] int @ 151011328     (524,288)
// sums [8,19,512] f32 @ 151535616     (311,296)
// counts [8,19]  f32 @ 151846912      (608)
#define OFF_Y3   0u
#define OFF_Y1   16777216u
#define OFF_Y2   83886080u
#define OFF_Y4   16777216u
#define OFF_MS   150994944u
#define OFF_LAB  151011328u
#define OFF_SUMS 151535616u
#define OFF_CNT  151846912u

// ---------------- conv1: reflect-pad 3->32, 256x256 ----------------
__global__ void conv1_k(const float* __restrict__ img, const float* __restrict__ w1,
                        float* __restrict__ y1) {
  int p  = blockIdx.x * 256 + threadIdx.x;   // 0..65535
  int oc = blockIdx.y, b = blockIdx.z;
  int y = p >> 8, x = p & 255;
  const float* wp = w1 + oc * 27;
  float acc = 0.f;
  for (int ic = 0; ic < 3; ++ic) {
    const float* ip = img + ((size_t)(b * 3 + ic)) * 65536;
#pragma unroll
    for (int ky = 0; ky < 3; ++ky) {
      int gy = y - 1 + ky; gy = gy < 0 ? -gy : (gy > 255 ? 510 - gy : gy);
#pragma unroll
      for (int kx = 0; kx < 3; ++kx) {
        int gx = x - 1 + kx; gx = gx < 0 ? -gx : (gx > 255 ? 510 - gx : gx);
        acc += ip[gy * 256 + gx] * wp[ic * 9 + ky * 3 + kx];
      }
    }
  }
  y1[((size_t)(b * 32 + oc)) * 65536 + p] = acc;
}

// ---------------- instance-norm stats (per plane) ----------------
__global__ void stats_k(const float* __restrict__ x, float2* __restrict__ ms, int HW) {
  int plane = blockIdx.x;
  const float* p = x + (size_t)plane * HW;
  float s = 0.f, sq = 0.f;
  for (int i = threadIdx.x; i < HW; i += 256) { float v = p[i]; s += v; sq += v * v; }
  __shared__ float ss[256], qq[256];
  ss[threadIdx.x] = s; qq[threadIdx.x] = sq; __syncthreads();
  for (int o = 128; o > 0; o >>= 1) {
    if (threadIdx.x < o) { ss[threadIdx.x] += ss[threadIdx.x + o]; qq[threadIdx.x] += qq[threadIdx.x + o]; }
    __syncthreads();
  }
  if (threadIdx.x == 0) {
    float m = ss[0] / HW;
    float v = qq[0] / HW - m * m;
    ms[plane] = make_float2(m, rsqrtf(fmaxf(v, 0.f) + 1e-5f));
  }
}

// ---------------- normalize + leaky-relu in place ----------------
__global__ void normlrelu_k(float* __restrict__ x, const float2* __restrict__ ms, int HW) {
  int plane = blockIdx.y;
  float2 m = ms[plane];
  int i = blockIdx.x * 256 + threadIdx.x;
  if (i < HW) {
    size_t idx = (size_t)plane * HW + i;
    float v = (x[idx] - m.x) * m.y;
    x[idx] = v >= 0.f ? v : 0.2f * v;
  }
}

// ---------------- stride-2 pad-1 3x3 conv (naive) ----------------
template <int IC>
__global__ void conv_s2_k(const float* __restrict__ in, const float* __restrict__ w,
                          float* __restrict__ out, int OC, int IH, int IW) {
  int OH = IH >> 1, OW = IW >> 1;
  int p  = blockIdx.x * 256 + threadIdx.x;
  int oc = blockIdx.y, b = blockIdx.z;
  int oy = p / OW, ox = p % OW;
  const float* wp = w + (size_t)oc * IC * 9;
  float acc = 0.f;
  for (int ic = 0; ic < IC; ++ic) {
    const float* ip = in + ((size_t)(b * IC + ic)) * IH * IW;
#pragma unroll
    for (int ky = 0; ky < 3; ++ky) {
      int iy = 2 * oy - 1 + ky;
      if (iy < 0 || iy >= IH) continue;
#pragma unroll
      for (int kx = 0; kx < 3; ++kx) {
        int ix = 2 * ox - 1 + kx;
        if (ix < 0 || ix >= IW) continue;
        acc += ip[iy * IW + ix] * wp[ic * 9 + ky * 3 + kx];
      }
    }
  }
  out[((size_t)(b * OC + oc)) * OH * OW + p] = acc;
}

// ---------------- ConvTranspose2d k3 s2 p1 op1 (128->256, 64->128) ----------------
__global__ void convT_k(const float* __restrict__ in, const float* __restrict__ wt,
                        float* __restrict__ out) {
  __shared__ float wl[128][12];
  int oc = blockIdx.y, b = blockIdx.z;
  int tid = threadIdx.x + threadIdx.y * 16;
  for (int t = tid; t < 128 * 9; t += 256) {
    int ic = t / 9, k = t % 9;
    wl[ic][k] = wt[((size_t)(ic * 256 + oc)) * 9 + k];
  }
  __syncthreads();
  int tile = blockIdx.x;
  int i = (tile >> 2) * 16 + threadIdx.y;  // input row 0..63
  int j = (tile & 3) * 16 + threadIdx.x;   // input col 0..63
  bool iok = (i + 1 < 64), jok = (j + 1 < 64);
  const float* ip = in + (size_t)b * 128 * 4096;
  float a00 = 0.f, a01 = 0.f, a10 = 0.f, a11 = 0.f;
  for (int ic = 0; ic < 128; ++ic) {
    const float* q = ip + (size_t)ic * 4096 + i * 64 + j;
    float v00 = q[0];
    float v01 = jok ? q[1] : 0.f;
    float v10 = iok ? q[64] : 0.f;
    float v11 = (iok && jok) ? q[65] : 0.f;
    a00 += wl[ic][4] * v00;
    a01 += wl[ic][5] * v00 + wl[ic][3] * v01;
    a10 += wl[ic][7] * v00 + wl[ic][1] * v10;
    a11 += wl[ic][8] * v00 + wl[ic][6] * v01 + wl[ic][2] * v10 + wl[ic][0] * v11;
  }
  float* op = out + ((size_t)(b * 256 + oc)) * 16384;
  int oy = 2 * i, ox = 2 * j;
  op[oy * 128 + ox]           = a00;
  op[oy * 128 + ox + 1]       = a01;
  op[(oy + 1) * 128 + ox]     = a10;
  op[(oy + 1) * 128 + ox + 1] = a11;
}

// ---------------- label map + counts from one-hot seg ----------------
__global__ void lab_k(const float* __restrict__ seg, int* __restrict__ lab,
                      float* __restrict__ counts) {
  __shared__ int hist[19];
  int t = threadIdx.x;
  if (t < 19) hist[t] = 0;
  __syncthreads();
  int b = blockIdx.y;
  int p = blockIdx.x * 256 + t;            // 0..16383
  int i = p >> 7, j = p & 127;
  const float* sp = seg + (size_t)b * 19 * 65536 + (2 * i) * 256 + 2 * j;
  int l = 0;
  for (int k = 0; k < 19; ++k) { if (sp[(size_t)k * 65536] != 0.f) { l = k; break; } }
  lab[b * 16384 + p] = l;
  atomicAdd(&hist[l], 1);
  __syncthreads();
  if (t < 19) atomicAdd(&counts[b * 19 + t], (float)hist[t]);
}

// ---------------- conv4: reflect-pad 256->512 3x3 + bias + tanh + segment sums ----------------
__global__ __launch_bounds__(256) void conv4_fused_k(
    const float* __restrict__ x, const float* __restrict__ w4, const float* __restrict__ b4,
    const int* __restrict__ lab, float* __restrict__ sums) {
  __shared__ float it[4][34][34];
  __shared__ float wl[4][16][12];
  __shared__ float bins[19][16];
  int tid = threadIdx.x;
  int tx = tid & 15, ty = tid >> 4;
  int tile = blockIdx.x;
  int y0 = (tile >> 2) * 32, x0 = (tile & 3) * 32;
  int oc0 = blockIdx.y * 16;
  int b = blockIdx.z;
  const float* xb = x + (size_t)b * 256 * 16384;
  float acc[16][4];
#pragma unroll
  for (int o = 0; o < 16; ++o)
#pragma unroll
    for (int p = 0; p < 4; ++p) acc[o][p] = 0.f;

  for (int ic0 = 0; ic0 < 256; ic0 += 4) {
    __syncthreads();
    for (int t = tid; t < 4 * 34 * 34; t += 256) {
      int ic = t / 1156, rem = t % 1156, r = rem / 34, c = rem % 34;
      int gy = y0 - 1 + r; gy = gy < 0 ? -gy : (gy > 127 ? 254 - gy : gy);
      int gx = x0 - 1 + c; gx = gx < 0 ? -gx : (gx > 127 ? 254 - gx : gx);
      it[ic][r][c] = xb[(size_t)(ic0 + ic) * 16384 + gy * 128 + gx];
    }
    for (int t = tid; t < 4 * 16 * 9; t += 256) {
      int ic = t / 144, rem = t % 144, o = rem / 9, k = rem % 9;
      wl[ic][o][k] = w4[(size_t)(oc0 + o) * 2304 + (ic0 + ic) * 9 + k];
    }
    __syncthreads();
#pragma unroll
    for (int ic = 0; ic < 4; ++ic) {
      float v[4][4];
#pragma unroll
      for (int r = 0; r < 4; ++r) {
        const float2* rp = (const float2*)&it[ic][2 * ty + r][2 * tx];
        float2 a = rp[0], bb = rp[1];
        v[r][0] = a.x; v[r][1] = a.y; v[r][2] = bb.x; v[r][3] = bb.y;
      }
#pragma unroll
      for (int o = 0; o < 16; ++o) {
        const float4* wp4 = (const float4*)&wl[ic][o][0];
        float4 wa = wp4[0], wb = wp4[1];
        float w8 = wl[ic][o][8];
        float w[9] = {wa.x, wa.y, wa.z, wa.w, wb.x, wb.y, wb.z, wb.w, w8};
#pragma unroll
        for (int py = 0; py < 2; ++py)
#pragma unroll
          for (int px = 0; px < 2; ++px) {
            float s = acc[o][py * 2 + px];
#pragma unroll
            for (int ky = 0; ky < 3; ++ky)
#pragma unroll
              for (int kx = 0; kx < 3; ++kx)
                s += w[ky * 3 + kx] * v[py + ky][px + kx];
            acc[o][py * 2 + px] = s;
          }
      }
    }
  }

  // epilogue: bias + tanh + per-label bins
  __syncthreads();
  for (int t = tid; t < 304; t += 256) ((float*)bins)[t] = 0.f;
  __syncthreads();
  float bl[16];
#pragma unroll
  for (int o = 0; o < 16; ++o) bl[o] = b4[oc0 + o];
  int lb[4];
#pragma unroll
  for (int py = 0; py < 2; ++py)
#pragma unroll
    for (int px = 0; px < 2; ++px)
      lb[py * 2 + px] = lab[b * 16384 + (y0 + 2 * ty + py) * 128 + (x0 + 2 * tx + px)];
#pragma unroll
  for (int o = 0; o < 16; ++o)
#pragma unroll
    for (int p = 0; p < 4; ++p) {
      float val = tanhf(acc[o][p] + bl[o]);
      atomicAdd(&bins[lb[p]][o], val);
    }
  __syncthreads();
  for (int t = tid; t < 304; t += 256) {
    int l = t >> 4, o = t & 15;
    atomicAdd(&sums[((size_t)b * 19 + l) * 512 + oc0 + o], bins[l][o]);
  }
}

// ---------------- finalize: means ----------------
__global__ void finalize_k(const float* __restrict__ sums, const float* __restrict__ counts,
                           float* __restrict__ out) {
  int idx = blockIdx.x * 256 + threadIdx.x;  // 77824 = 304*256
  int bl = idx / 512;
  float c = counts[bl];
  out[idx] = c > 0.f ? sums[idx] / fmaxf(c, 1.f) : 0.f;
}

extern "C" void kernel_launch(void* const* d_in, const int* in_sizes, int n_in,
                              void* d_out, int out_size, void* d_ws, size_t ws_size,
                              hipStream_t stream) {
  const float* image = (const float*)d_in[0];
  const float* seg   = (const float*)d_in[1];
  const float* w1    = (const float*)d_in[2];
  const float* w2    = (const float*)d_in[4];
  const float* w3    = (const float*)d_in[6];
  const float* wt    = (const float*)d_in[8];
  const float* w4    = (const float*)d_in[10];
  const float* b4    = (const float*)d_in[11];
  float* out = (float*)d_out;
  char* ws = (char*)d_ws;

  float*  y1     = (float*)(ws + OFF_Y1);
  float*  y2     = (float*)(ws + OFF_Y2);
  float*  y3     = (float*)(ws + OFF_Y3);
  float*  y4     = (float*)(ws + OFF_Y4);
  float2* ms     = (float2*)(ws + OFF_MS);
  int*    lab    = (int*)(ws + OFF_LAB);
  float*  sums   = (float*)(ws + OFF_SUMS);
  float*  counts = (float*)(ws + OFF_CNT);

  hipMemsetAsync(ws + OFF_SUMS, 0, 311296 + 608, stream);

  // conv1 + inorm + lrelu
  conv1_k<<<dim3(256, 32, 8), 256, 0, stream>>>(image, w1, y1);
  stats_k<<<256, 256, 0, stream>>>(y1, ms, 65536);
  normlrelu_k<<<dim3(256, 256), 256, 0, stream>>>(y1, ms, 65536);

  // conv2 + inorm + lrelu
  conv_s2_k<32><<<dim3(64, 64, 8), 256, 0, stream>>>(y1, w2, y2, 64, 256, 256);
  stats_k<<<512, 256, 0, stream>>>(y2, ms, 16384);
  normlrelu_k<<<dim3(64, 512), 256, 0, stream>>>(y2, ms, 16384);

  // conv3 + inorm + lrelu
  conv_s2_k<64><<<dim3(16, 128, 8), 256, 0, stream>>>(y2, w3, y3, 128, 128, 128);
  stats_k<<<1024, 256, 0, stream>>>(y3, ms, 4096);
  normlrelu_k<<<dim3(16, 1024), 256, 0, stream>>>(y3, ms, 4096);

  // convT + inorm + lrelu
  convT_k<<<dim3(16, 256, 8), dim3(16, 16), 0, stream>>>(y3, wt, y4);
  stats_k<<<2048, 256, 0, stream>>>(y4, ms, 16384);
  normlrelu_k<<<dim3(64, 2048), 256, 0, stream>>>(y4, ms, 16384);

  // labels + counts
  lab_k<<<dim3(64, 8), 256, 0, stream>>>(seg, lab, counts);

  // conv4 + bias + tanh + fused segment sums
  conv4_fused_k<<<dim3(16, 32, 8), 256, 0, stream>>>(y4, w4, b4, lab, sums);

  // style codes
  finalize_k<<<304, 256, 0, stream>>>(sums, counts, out);
}

// Round 2
// 3811.725 us; speedup vs baseline: 2.3173x; 2.3173x over previous
//
#include <hip/hip_runtime.h>
#include <hip/hip_bf16.h>
#include <math.h>

typedef __attribute__((ext_vector_type(8))) short bf16x8;
typedef __attribute__((ext_vector_type(8))) unsigned short u16x8;
typedef __attribute__((ext_vector_type(4))) float f32x4;

// ---------------- workspace layout (bytes) ----------------
// y1  [8,32,256,256]  f32  @ 0          (67,108,864)   dead after conv2
// y2  [8,64,128,128]  f32  @ 67108864   (33,554,432)   dead after conv3
// y3  [8,128,64,64]   f32  @ 100663296  (16,777,216)   dead after convT
// y4b [8,256,128,128] bf16 @ 0          (67,108,864)   overlaps y1 (dead)
// xq  [8,128,128,256] bf16 @ 67108864   (67,108,864)   overlaps y2+y3 (dead)
// wb  [512,9,256]     bf16 @ 134217728  (2,359,296)
// ms  2048 float2          @ 136577024  (16,384)
// lab [8,128,128]     int  @ 136593408  (524,288)
// sums[8,19,512]      f32  @ 137117696  (311,296)
// cnt [8,19]          f32  @ 137428992  (608)
#define OFF_Y1   0u
#define OFF_Y2   67108864u
#define OFF_Y3   100663296u
#define OFF_Y4B  0u
#define OFF_XQ   67108864u
#define OFF_WB   134217728u
#define OFF_MS   136577024u
#define OFF_LAB  136593408u
#define OFF_SUMS 137117696u
#define OFF_CNT  137428992u

__device__ __forceinline__ float bfu2f(unsigned short u) {
  return __builtin_bit_cast(float, ((unsigned)u) << 16);
}
__device__ __forceinline__ unsigned short f2bfu(float f) {
  __hip_bfloat16 h = __float2bfloat16(f);
  return __builtin_bit_cast(unsigned short, h);
}
__device__ __forceinline__ void gload_lds16(const void* g, void* l) {
  __builtin_amdgcn_global_load_lds(
      (const __attribute__((address_space(1))) unsigned int*)g,
      (__attribute__((address_space(3))) unsigned int*)l, 16, 0, 0);
}

// ---------------- conv1: reflect-pad 3->32, 256x256 ----------------
__global__ void conv1_k(const float* __restrict__ img, const float* __restrict__ w1,
                        float* __restrict__ y1) {
  int p  = blockIdx.x * 256 + threadIdx.x;
  int oc = blockIdx.y, b = blockIdx.z;
  int y = p >> 8, x = p & 255;
  const float* wp = w1 + oc * 27;
  float acc = 0.f;
  for (int ic = 0; ic < 3; ++ic) {
    const float* ip = img + ((size_t)(b * 3 + ic)) * 65536;
#pragma unroll
    for (int ky = 0; ky < 3; ++ky) {
      int gy = y - 1 + ky; gy = gy < 0 ? -gy : (gy > 255 ? 510 - gy : gy);
#pragma unroll
      for (int kx = 0; kx < 3; ++kx) {
        int gx = x - 1 + kx; gx = gx < 0 ? -gx : (gx > 255 ? 510 - gx : gx);
        acc += ip[gy * 256 + gx] * wp[ic * 9 + ky * 3 + kx];
      }
    }
  }
  y1[((size_t)(b * 32 + oc)) * 65536 + p] = acc;
}

// ---------------- instance-norm stats (f32 planes) ----------------
__global__ void stats_k(const float* __restrict__ x, float2* __restrict__ ms, int HW) {
  int plane = blockIdx.x;
  const float* p = x + (size_t)plane * HW;
  float s = 0.f, sq = 0.f;
  for (int i = threadIdx.x; i < HW; i += 256) { float v = p[i]; s += v; sq += v * v; }
  __shared__ float ss[256], qq[256];
  ss[threadIdx.x] = s; qq[threadIdx.x] = sq; __syncthreads();
  for (int o = 128; o > 0; o >>= 1) {
    if (threadIdx.x < o) { ss[threadIdx.x] += ss[threadIdx.x + o]; qq[threadIdx.x] += qq[threadIdx.x + o]; }
    __syncthreads();
  }
  if (threadIdx.x == 0) {
    float m = ss[0] / HW;
    float v = qq[0] / HW - m * m;
    ms[plane] = make_float2(m, rsqrtf(fmaxf(v, 0.f) + 1e-5f));
  }
}

// ---------------- instance-norm stats (bf16 planes) ----------------
__global__ void stats_bf_k(const unsigned short* __restrict__ x, float2* __restrict__ ms, int HW) {
  int plane = blockIdx.x;
  const u16x8* p = (const u16x8*)(x + (size_t)plane * HW);
  float s = 0.f, sq = 0.f;
  for (int i = threadIdx.x; i < HW / 8; i += 256) {
    u16x8 v = p[i];
#pragma unroll
    for (int e = 0; e < 8; ++e) { float f = bfu2f(v[e]); s += f; sq += f * f; }
  }
  __shared__ float ss[256], qq[256];
  ss[threadIdx.x] = s; qq[threadIdx.x] = sq; __syncthreads();
  for (int o = 128; o > 0; o >>= 1) {
    if (threadIdx.x < o) { ss[threadIdx.x] += ss[threadIdx.x + o]; qq[threadIdx.x] += qq[threadIdx.x + o]; }
    __syncthreads();
  }
  if (threadIdx.x == 0) {
    float m = ss[0] / HW;
    float v = qq[0] / HW - m * m;
    ms[plane] = make_float2(m, rsqrtf(fmaxf(v, 0.f) + 1e-5f));
  }
}

// ---------------- normalize + leaky-relu in place (f32) ----------------
__global__ void normlrelu_k(float* __restrict__ x, const float2* __restrict__ ms, int HW) {
  int plane = blockIdx.y;
  float2 m = ms[plane];
  int i = blockIdx.x * 256 + threadIdx.x;
  if (i < HW) {
    size_t idx = (size_t)plane * HW + i;
    float v = (x[idx] - m.x) * m.y;
    x[idx] = v >= 0.f ? v : 0.2f * v;
  }
}

// ---------------- stride-2 pad-1 3x3 conv (naive f32) ----------------
template <int IC>
__global__ void conv_s2_k(const float* __restrict__ in, const float* __restrict__ w,
                          float* __restrict__ out, int OC, int IH, int IW) {
  int OH = IH >> 1, OW = IW >> 1;
  int p  = blockIdx.x * 256 + threadIdx.x;
  int oc = blockIdx.y, b = blockIdx.z;
  int oy = p / OW, ox = p % OW;
  const float* wp = w + (size_t)oc * IC * 9;
  float acc = 0.f;
  for (int ic = 0; ic < IC; ++ic) {
    const float* ip = in + ((size_t)(b * IC + ic)) * IH * IW;
#pragma unroll
    for (int ky = 0; ky < 3; ++ky) {
      int iy = 2 * oy - 1 + ky;
      if (iy < 0 || iy >= IH) continue;
#pragma unroll
      for (int kx = 0; kx < 3; ++kx) {
        int ix = 2 * ox - 1 + kx;
        if (ix < 0 || ix >= IW) continue;
        acc += ip[iy * IW + ix] * wp[ic * 9 + ky * 3 + kx];
      }
    }
  }
  out[((size_t)(b * OC + oc)) * OH * OW + p] = acc;
}

// ---------------- ConvTranspose2d k3 s2 p1 op1 -> bf16 NCHW ----------------
__global__ void convT_k(const float* __restrict__ in, const float* __restrict__ wt,
                        unsigned short* __restrict__ out) {
  __shared__ float wl[128][12];
  int oc = blockIdx.y, b = blockIdx.z;
  int tid = threadIdx.x + threadIdx.y * 16;
  for (int t = tid; t < 128 * 9; t += 256) {
    int ic = t / 9, k = t % 9;
    wl[ic][k] = wt[((size_t)(ic * 256 + oc)) * 9 + k];
  }
  __syncthreads();
  int tile = blockIdx.x;
  int i = (tile >> 2) * 16 + threadIdx.y;
  int j = (tile & 3) * 16 + threadIdx.x;
  bool iok = (i + 1 < 64), jok = (j + 1 < 64);
  const float* ip = in + (size_t)b * 128 * 4096;
  float a00 = 0.f, a01 = 0.f, a10 = 0.f, a11 = 0.f;
  for (int ic = 0; ic < 128; ++ic) {
    const float* q = ip + (size_t)ic * 4096 + i * 64 + j;
    float v00 = q[0];
    float v01 = jok ? q[1] : 0.f;
    float v10 = iok ? q[64] : 0.f;
    float v11 = (iok && jok) ? q[65] : 0.f;
    a00 += wl[ic][4] * v00;
    a01 += wl[ic][5] * v00 + wl[ic][3] * v01;
    a10 += wl[ic][7] * v00 + wl[ic][1] * v10;
    a11 += wl[ic][8] * v00 + wl[ic][6] * v01 + wl[ic][2] * v10 + wl[ic][0] * v11;
  }
  unsigned short* op = out + ((size_t)(b * 256 + oc)) * 16384;
  int oy = 2 * i, ox = 2 * j;
  op[oy * 128 + ox]           = f2bfu(a00);
  op[oy * 128 + ox + 1]       = f2bfu(a01);
  op[(oy + 1) * 128 + ox]     = f2bfu(a10);
  op[(oy + 1) * 128 + ox + 1] = f2bfu(a11);
}

// ---------------- norm+lrelu y4b (bf16 NCHW) -> xq (bf16 NHWC) ----------------
__global__ __launch_bounds__(256) void pack4_k(const unsigned short* __restrict__ y4,
                                               const float2* __restrict__ ms,
                                               unsigned short* __restrict__ xq) {
  __shared__ unsigned short tile[64][136];  // 272B rows: 16B-aligned, odd 16B count
  int tid = threadIdx.x;
  int sy = blockIdx.x, c0 = blockIdx.y * 64, b = blockIdx.z;
#pragma unroll
  for (int i = 0; i < 4; ++i) {
    int idx = i * 256 + tid;          // 0..1023
    int c = idx >> 4, x8 = idx & 15;
    int plane = b * 256 + c0 + c;
    u16x8 v = *(const u16x8*)(y4 + (size_t)plane * 16384 + sy * 128 + x8 * 8);
    float2 m = ms[plane];
    u16x8 o;
#pragma unroll
    for (int e = 0; e < 8; ++e) {
      float f = (bfu2f(v[e]) - m.x) * m.y;
      f = f >= 0.f ? f : 0.2f * f;
      o[e] = f2bfu(f);
    }
    *(u16x8*)&tile[c][x8 * 8] = o;
  }
  __syncthreads();
#pragma unroll
  for (int i = 0; i < 4; ++i) {
    int idx = i * 256 + tid;          // 0..1023
    int x = idx >> 3, seg = idx & 7;
    u16x8 o;
#pragma unroll
    for (int j = 0; j < 8; ++j) o[j] = tile[seg * 8 + j][x];
    *(u16x8*)(xq + ((size_t)(b * 16384 + sy * 128 + x)) * 256 + c0 + seg * 8) = o;
  }
}

// ---------------- weight repack: OIHW f32 -> [oc][9][ic] bf16 ----------------
__global__ void wprep_k(const float* __restrict__ w4, unsigned short* __restrict__ wb) {
  int idx = blockIdx.x * 256 + threadIdx.x;  // < 1179648
  int n = idx / 2304, r = idx % 2304, kk = r / 256, ic = r % 256;
  wb[idx] = f2bfu(w4[n * 2304 + ic * 9 + kk]);
}

// ---------------- label map + counts from one-hot seg ----------------
__global__ void lab_k(const float* __restrict__ seg, int* __restrict__ lab,
                      float* __restrict__ counts) {
  __shared__ int hist[19];
  int t = threadIdx.x;
  if (t < 19) hist[t] = 0;
  __syncthreads();
  int b = blockIdx.y;
  int p = blockIdx.x * 256 + t;
  int i = p >> 7, j = p & 127;
  const float* sp = seg + (size_t)b * 19 * 65536 + (2 * i) * 256 + 2 * j;
  int l = 0;
  for (int k = 0; k < 19; ++k) { if (sp[(size_t)k * 65536] != 0.f) { l = k; break; } }
  lab[b * 16384 + p] = l;
  atomicAdd(&hist[l], 1);
  __syncthreads();
  if (t < 19) atomicAdd(&counts[b * 19 + t], (float)hist[t]);
}

// ---------------- conv4 as bf16 MFMA implicit GEMM + fused epilogue ----------------
// tile: BM=128 spatial (one image row y), BN=128 oc, BK=64 ic; 9 kernel positions.
// LDS: As [128][64] bf16 (16KB, XOR-swizzled), Bs same, labs[128].
__global__ __launch_bounds__(256) void conv4_mfma_k(
    const unsigned short* __restrict__ xq, const unsigned short* __restrict__ wb,
    const float* __restrict__ b4, const int* __restrict__ lab, float* __restrict__ sums) {
  __shared__ char smem[33280];
  char* As = smem;
  char* Bs = smem + 16384;
  int* labs = (int*)(smem + 32768);
  int tid = threadIdx.x;
  int y = blockIdx.x, nblk = blockIdx.y, b = blockIdx.z;
  int n0 = nblk * 128;
  if (tid < 128) labs[tid] = lab[b * 16384 + y * 128 + tid];
  int lane = tid & 63, w = tid >> 6;
  int wm = w >> 1, wn = w & 1;
  int lr = lane & 15, lg = lane >> 4;

  f32x4 acc[4][4];
#pragma unroll
  for (int a = 0; a < 4; ++a)
#pragma unroll
    for (int c = 0; c < 4; ++c) acc[a][c] = (f32x4){0.f, 0.f, 0.f, 0.f};

  const unsigned short* xb = xq + (size_t)b * (128 * 128 * 256);

  // staging geometry: phys 16B-block pb = i*256+tid; row = pb>>3; swizzled ic offset.
  int rowS[4], icof[4], Pb[4];
#pragma unroll
  for (int i = 0; i < 4; ++i) {
    int pb = i * 256 + tid;
    Pb[i] = pb * 16;
    rowS[i] = pb >> 3;
    icof[i] = ((pb & 7) ^ (rowS[i] & 7)) << 3;
  }

  for (int kk = 0; kk < 9; ++kk) {
    int ky = kk / 3, kx = kk % 3;
    int sy = y + ky - 1; sy = sy < 0 ? 1 : (sy > 127 ? 126 : sy);
    for (int ic0 = 0; ic0 < 256; ic0 += 64) {
      __syncthreads();
#pragma unroll
      for (int i = 0; i < 4; ++i) {  // A: [128 x][64 ic]
        int m = rowS[i];
        int sx = m + kx - 1; sx = sx < 0 ? 1 : (sx > 127 ? 126 : sx);
        gload_lds16(xb + ((size_t)(sy * 128 + sx)) * 256 + ic0 + icof[i], As + Pb[i]);
      }
#pragma unroll
      for (int i = 0; i < 4; ++i) {  // B: [128 oc][64 ic]
        int n = rowS[i];
        gload_lds16(wb + ((size_t)((n0 + n) * 9 + kk)) * 256 + ic0 + icof[i], Bs + Pb[i]);
      }
      __syncthreads();

      bf16x8 af[4][2], bfr[4][2];
#pragma unroll
      for (int mi = 0; mi < 4; ++mi)
#pragma unroll
        for (int kh = 0; kh < 2; ++kh) {
          int row = wm * 64 + mi * 16 + lr;
          int byte = (row << 7) + kh * 64 + lg * 16;
          byte ^= (row & 7) << 4;
          af[mi][kh] = *(const bf16x8*)(As + byte);
        }
#pragma unroll
      for (int ni = 0; ni < 4; ++ni)
#pragma unroll
        for (int kh = 0; kh < 2; ++kh) {
          int row = wn * 64 + ni * 16 + lr;
          int byte = (row << 7) + kh * 64 + lg * 16;
          byte ^= (row & 7) << 4;
          bfr[ni][kh] = *(const bf16x8*)(Bs + byte);
        }
#pragma unroll
      for (int mi = 0; mi < 4; ++mi)
#pragma unroll
        for (int ni = 0; ni < 4; ++ni)
#pragma unroll
          for (int kh = 0; kh < 2; ++kh)
            acc[mi][ni] = __builtin_amdgcn_mfma_f32_16x16x32_bf16(
                af[mi][kh], bfr[ni][kh], acc[mi][ni], 0, 0, 0);
    }
  }

  // epilogue: bias + tanh + per-label bins (reuse As/Bs LDS)
  __syncthreads();
  float* bins = (float*)smem;  // [19][128]
  for (int t2 = tid; t2 < 19 * 128; t2 += 256) bins[t2] = 0.f;
  __syncthreads();
  float bias[4];
#pragma unroll
  for (int ni = 0; ni < 4; ++ni) bias[ni] = b4[n0 + wn * 64 + ni * 16 + lr];
#pragma unroll
  for (int mi = 0; mi < 4; ++mi)
#pragma unroll
    for (int ni = 0; ni < 4; ++ni) {
      int ct = wn * 64 + ni * 16 + lr;
#pragma unroll
      for (int r = 0; r < 4; ++r) {
        int x = wm * 64 + mi * 16 + lg * 4 + r;
        float v = tanhf(acc[mi][ni][r] + bias[ni]);
        atomicAdd(&bins[labs[x] * 128 + ct], v);
      }
    }
  __syncthreads();
  for (int t2 = tid; t2 < 19 * 128; t2 += 256) {
    float v = bins[t2];
    if (v != 0.f)
      atomicAdd(&sums[((size_t)(b * 19 + (t2 >> 7))) * 512 + n0 + (t2 & 127)], v);
  }
}

// ---------------- finalize: means ----------------
__global__ void finalize_k(const float* __restrict__ sums, const float* __restrict__ counts,
                           float* __restrict__ out) {
  int idx = blockIdx.x * 256 + threadIdx.x;  // 77824 = 304*256
  int bl = idx / 512;
  float c = counts[bl];
  out[idx] = c > 0.f ? sums[idx] / fmaxf(c, 1.f) : 0.f;
}

extern "C" void kernel_launch(void* const* d_in, const int* in_sizes, int n_in,
                              void* d_out, int out_size, void* d_ws, size_t ws_size,
                              hipStream_t stream) {
  const float* image = (const float*)d_in[0];
  const float* seg   = (const float*)d_in[1];
  const float* w1    = (const float*)d_in[2];
  const float* w2    = (const float*)d_in[4];
  const float* w3    = (const float*)d_in[6];
  const float* wt    = (const float*)d_in[8];
  const float* w4    = (const float*)d_in[10];
  const float* b4    = (const float*)d_in[11];
  float* out = (float*)d_out;
  char* ws = (char*)d_ws;

  float*          y1     = (float*)(ws + OFF_Y1);
  float*          y2     = (float*)(ws + OFF_Y2);
  float*          y3     = (float*)(ws + OFF_Y3);
  unsigned short* y4b    = (unsigned short*)(ws + OFF_Y4B);
  unsigned short* xq     = (unsigned short*)(ws + OFF_XQ);
  unsigned short* wbb    = (unsigned short*)(ws + OFF_WB);
  float2*         ms     = (float2*)(ws + OFF_MS);
  int*            lab    = (int*)(ws + OFF_LAB);
  float*          sums   = (float*)(ws + OFF_SUMS);
  float*          counts = (float*)(ws + OFF_CNT);

  hipMemsetAsync(ws + OFF_SUMS, 0, 311296 + 608, stream);

  // conv1 + inorm + lrelu
  conv1_k<<<dim3(256, 32, 8), 256, 0, stream>>>(image, w1, y1);
  stats_k<<<256, 256, 0, stream>>>(y1, ms, 65536);
  normlrelu_k<<<dim3(256, 256), 256, 0, stream>>>(y1, ms, 65536);

  // conv2 + inorm + lrelu
  conv_s2_k<32><<<dim3(64, 64, 8), 256, 0, stream>>>(y1, w2, y2, 64, 256, 256);
  stats_k<<<512, 256, 0, stream>>>(y2, ms, 16384);
  normlrelu_k<<<dim3(64, 512), 256, 0, stream>>>(y2, ms, 16384);

  // conv3 + inorm + lrelu
  conv_s2_k<64><<<dim3(16, 128, 8), 256, 0, stream>>>(y2, w3, y3, 128, 128, 128);
  stats_k<<<1024, 256, 0, stream>>>(y3, ms, 4096);
  normlrelu_k<<<dim3(16, 1024), 256, 0, stream>>>(y3, ms, 4096);

  // convT -> bf16 NCHW; stats; norm+lrelu+transpose -> NHWC bf16
  convT_k<<<dim3(16, 256, 8), dim3(16, 16), 0, stream>>>(y3, wt, y4b);
  stats_bf_k<<<2048, 256, 0, stream>>>(y4b, ms, 16384);
  pack4_k<<<dim3(128, 4, 8), 256, 0, stream>>>(y4b, ms, xq);

  // weights + labels
  wprep_k<<<4608, 256, 0, stream>>>(w4, wbb);
  lab_k<<<dim3(64, 8), 256, 0, stream>>>(seg, lab, counts);

  // conv4 MFMA + bias + tanh + fused segment sums
  conv4_mfma_k<<<dim3(128, 4, 8), 256, 0, stream>>>(xq, wbb, b4, lab, sums);

  // style codes
  finalize_k<<<304, 256, 0, stream>>>(sums, counts, out);
}

// Round 3
// 886.713 us; speedup vs baseline: 9.9612x; 4.2987x over previous
//
#include <hip/hip_runtime.h>
#include <hip/hip_bf16.h>
#include <math.h>

typedef __attribute__((ext_vector_type(8))) short bf16x8;
typedef __attribute__((ext_vector_type(8))) unsigned short u16x8;
typedef __attribute__((ext_vector_type(4))) float f32x4;

// ---------------- workspace layout (bytes) ----------------
// x1  [8,258,258,32] bf16 @ 0           (34,080,768)  zero-padded NHWC
// x2  [8,130,130,64] bf16 @ 34080768    (17,305,600)  zero-padded NHWC
// x3  [8,65,65,128]  bf16 @ 51386368    (8,652,800)   high-side pad NHWC
// y4  [8,128,128,256]bf16 @ 60039168    (67,108,864)  NHWC
// wb4 [512,9,256]    bf16 @ 127148032   (2,359,296)
// wb2 [64,10,32]     bf16 @ 129507328   (40,960)      zero 10th tap
// wb3 [128,9,64]     bf16 @ 129548288   (147,456)
// wbt [1024,512]     bf16 @ 129695744   (1,048,576)   unified convT B
// st1..st4 / sums / cnt @ 130744320     (342,624)     zeroed each call
// ms1..ms4 float2       @ 131086944
// lab [8,128,128] int   @ 131117664    (524,288)
#define OFF_X1   0ull
#define OFF_X2   34080768ull
#define OFF_X3   51386368ull
#define OFF_Y4   60039168ull
#define OFF_WB4  127148032ull
#define OFF_WB2  129507328ull
#define OFF_WB3  129548288ull
#define OFF_WBT  129695744ull
#define OFF_ST1  130744320ull
#define OFF_ST2  130746368ull
#define OFF_ST3  130750464ull
#define OFF_ST4  130758656ull
#define OFF_SUMS 130775040ull
#define OFF_CNT  131086336ull
#define OFF_MS1  131086944ull
#define OFF_MS2  131088992ull
#define OFF_MS3  131093088ull
#define OFF_MS4  131101280ull
#define OFF_LAB  131117664ull

__device__ __forceinline__ float bfu2f(unsigned short u) {
  return __builtin_bit_cast(float, ((unsigned)u) << 16);
}
__device__ __forceinline__ unsigned short f2bfu(float f) {
  __hip_bfloat16 h = __float2bfloat16(f);
  return __builtin_bit_cast(unsigned short, h);
}
__device__ __forceinline__ void gload_lds16(const void* g, void* l) {
  __builtin_amdgcn_global_load_lds(
      (const __attribute__((address_space(1))) unsigned int*)g,
      (__attribute__((address_space(3))) unsigned int*)l, 16, 0, 0);
}

// ---------------- conv1: reflect-pad 3->32 -> x1 NHWC padded bf16 ----------------
__global__ __launch_bounds__(256) void conv1_k(const float* __restrict__ img,
                                               const float* __restrict__ w1,
                                               unsigned short* __restrict__ x1) {
  __shared__ float wl[864];  // [k 27][oc 32]
  int t = threadIdx.x, y = blockIdx.x, b = blockIdx.y;
  for (int i = t; i < 864; i += 256) wl[i] = w1[(i & 31) * 27 + (i >> 5)];
  __syncthreads();
  int x = t;
  float val[27];
  for (int ic = 0; ic < 3; ++ic) {
    const float* ip = img + ((size_t)(b * 3 + ic)) * 65536;
#pragma unroll
    for (int ky = 0; ky < 3; ++ky) {
      int gy = y - 1 + ky; gy = gy < 0 ? -gy : (gy > 255 ? 510 - gy : gy);
#pragma unroll
      for (int kx = 0; kx < 3; ++kx) {
        int gx = x - 1 + kx; gx = gx < 0 ? -gx : (gx > 255 ? 510 - gx : gx);
        val[ic * 9 + ky * 3 + kx] = ip[gy * 256 + gx];
      }
    }
  }
  float a[32];
#pragma unroll
  for (int oc = 0; oc < 32; ++oc) a[oc] = 0.f;
#pragma unroll
  for (int k = 0; k < 27; ++k) {
    float vv = val[k];
#pragma unroll
    for (int oc = 0; oc < 32; ++oc) a[oc] += wl[k * 32 + oc] * vv;
  }
  unsigned short ov[32];
#pragma unroll
  for (int oc = 0; oc < 32; ++oc) ov[oc] = f2bfu(a[oc]);
  unsigned short* op = x1 + ((size_t)(b * 258 + y + 1) * 258 + (x + 1)) * 32;
#pragma unroll
  for (int i = 0; i < 4; ++i) *(u16x8*)(op + i * 8) = *(const u16x8*)(ov + i * 8);
}

// ---------------- generic NHWC channel stats (sum, sumsq) ----------------
template <int C>
__global__ void statsn_k(const unsigned short* __restrict__ base, int rowStride, int unitsLog,
                         int rowsPer, long bStride, float* __restrict__ stats) {
  const int CH8 = C / 8;
  __shared__ float bins[C * 2];
  int tid = threadIdx.x, slice = blockIdx.x, b = blockIdx.y;
  for (int i = tid; i < C * 2; i += 256) bins[i] = 0.f;
  __syncthreads();
  const unsigned short* bp = base + (size_t)b * bStride + (size_t)(slice * rowsPer) * rowStride;
  int total = rowsPer << unitsLog;
  float s8[8] = {0, 0, 0, 0, 0, 0, 0, 0}, q8[8] = {0, 0, 0, 0, 0, 0, 0, 0};
  for (int idx = tid; idx < total; idx += 256) {
    int rl = idx >> unitsLog, ux = idx & ((1 << unitsLog) - 1);
    u16x8 v = *(const u16x8*)(bp + (size_t)rl * rowStride + ux * 8);
#pragma unroll
    for (int e = 0; e < 8; ++e) { float f = bfu2f(v[e]); s8[e] += f; q8[e] += f * f; }
  }
#pragma unroll
  for (int e = 0; e < 8; ++e)
    for (int off = 32; off >= CH8; off >>= 1) {
      s8[e] += __shfl_xor(s8[e], off);
      q8[e] += __shfl_xor(q8[e], off);
    }
  int lane = tid & 63;
  if (lane < CH8) {
#pragma unroll
    for (int e = 0; e < 8; ++e) {
      atomicAdd(&bins[(lane * 8 + e) * 2], s8[e]);
      atomicAdd(&bins[(lane * 8 + e) * 2 + 1], q8[e]);
    }
  }
  __syncthreads();
  for (int i = tid; i < C * 2; i += 256) atomicAdd(&stats[b * C * 2 + i], bins[i]);
}

// ---------------- stats -> (mean, rstd) ----------------
__global__ void msn_k(const float* __restrict__ st, float2* __restrict__ ms, float invN, int total) {
  int i = blockIdx.x * 256 + threadIdx.x;
  if (i < total) {
    float m = st[2 * i] * invN;
    float v = st[2 * i + 1] * invN - m * m;
    ms[i] = make_float2(m, rsqrtf(fmaxf(v, 0.f) + 1e-5f));
  }
}

// ---------------- normalize + leaky-relu in place (NHWC bf16, interior) ----------------
template <int C>
__global__ void nln_k(unsigned short* __restrict__ base, int rowStride, int unitsPerRow,
                      long bStride, const float2* __restrict__ ms) {
  const int CH8 = C / 8;
  int row = blockIdx.x, b = blockIdx.y;
  unsigned short* rp = base + (size_t)b * bStride + (size_t)row * rowStride;
  const float2* msb = ms + b * C;
  for (int idx = threadIdx.x; idx < unitsPerRow; idx += 256) {
    u16x8 v = *(u16x8*)(rp + idx * 8);
    int ch = (idx & (CH8 - 1)) * 8;
    u16x8 o;
#pragma unroll
    for (int e = 0; e < 8; ++e) {
      float2 m = msb[ch + e];
      float f = (bfu2f(v[e]) - m.x) * m.y;
      o[e] = f2bfu(f >= 0.f ? f : 0.2f * f);
    }
    *(u16x8*)(rp + idx * 8) = o;
  }
}

// ---------------- weight repacks ----------------
__global__ void wrep2_k(const float* __restrict__ w2, unsigned short* __restrict__ wb2) {
  int idx = blockIdx.x * 256 + threadIdx.x;  // 64*320
  if (idx >= 20480) return;
  int oc = idx / 320, r = idx % 320, tap = r >> 5, ic = r & 31;
  wb2[idx] = tap < 9 ? f2bfu(w2[(oc * 32 + ic) * 9 + tap]) : (unsigned short)0;
}
__global__ void wrep3_k(const float* __restrict__ w3, unsigned short* __restrict__ wb3) {
  int idx = blockIdx.x * 256 + threadIdx.x;  // 128*9*64 = 73728
  int oc = idx / 576, r = idx % 576, tap = r >> 6, ic = r & 63;
  wb3[idx] = f2bfu(w3[(oc * 64 + ic) * 9 + tap]);
}
__device__ const int c_taptab[16] = {4, -1, -1, -1, 5, 3, -1, -1, 7, -1, 1, -1, 8, 6, 2, 0};
__global__ void wrepT_k(const float* __restrict__ wt, unsigned short* __restrict__ wbt) {
  int idx = blockIdx.x * 256 + threadIdx.x;  // 1024*512
  int n = idx >> 9, k = idx & 511;
  int cl = n >> 8, oc = n & 255, nb = k >> 7, ic = k & 127;
  int tap = c_taptab[cl * 4 + nb];
  wbt[idx] = tap < 0 ? (unsigned short)0 : f2bfu(wt[(ic * 256 + oc) * 9 + tap]);
}
__global__ void wrep4_k(const float* __restrict__ w4, unsigned short* __restrict__ wb) {
  int idx = blockIdx.x * 256 + threadIdx.x;  // 512*9*256
  int n = idx / 2304, r = idx % 2304, kk = r / 256, ic = r % 256;
  wb[idx] = f2bfu(w4[n * 2304 + ic * 9 + kk]);
}

// ---------------- conv2 MFMA: x1[8,258,258,32] -> x2[8,130,130,64] + stats ----------------
// BM=128 (row y, x 0..127), BN=64, K=320 (10 taps x 32ch, tap9=0), BK=64.
__global__ __launch_bounds__(256) void conv2_k(const unsigned short* __restrict__ x1,
                                               const unsigned short* __restrict__ wb2,
                                               unsigned short* __restrict__ x2,
                                               float* __restrict__ st2) {
  __shared__ char smem[25088];
  char* As = smem;                       // [128][64] bf16
  char* Bs = smem + 16384;               // [64][64] bf16
  float* bins = (float*)(smem + 24576);  // [64][2]
  int tid = threadIdx.x, y = blockIdx.x, b = blockIdx.y;
  int lane = tid & 63, w = tid >> 6, wm = w >> 1, wn = w & 1;
  int lr = lane & 15, lg = lane >> 4;
  f32x4 acc[4][2];
#pragma unroll
  for (int i = 0; i < 4; ++i)
#pragma unroll
    for (int j = 0; j < 2; ++j) acc[i][j] = (f32x4){0.f, 0.f, 0.f, 0.f};

  int rowA[4], lcA[4], PbA[4];
#pragma unroll
  for (int i = 0; i < 4; ++i) {
    int pb = i * 256 + tid;
    PbA[i] = pb * 16; rowA[i] = pb >> 3; lcA[i] = (pb & 7) ^ (rowA[i] & 7);
  }
  int rowB[2], lcB[2], PbB[2];
#pragma unroll
  for (int i = 0; i < 2; ++i) {
    int pb = i * 256 + tid;
    PbB[i] = pb * 16; rowB[i] = pb >> 3; lcB[i] = (pb & 7) ^ (rowB[i] & 7);
  }
  const unsigned short* xb = x1 + (size_t)b * 2130048;

  for (int kb = 0; kb < 5; ++kb) {
    __syncthreads();
#pragma unroll
    for (int i = 0; i < 4; ++i) {
      int tp = kb * 2 + (lcA[i] >> 2);
      int ky = (tp * 11) >> 5;  // tp/3 for tp<=9
      int kx = tp - ky * 3;
      gload_lds16(xb + ((size_t)((2 * y + ky) * 258 + 2 * rowA[i] + kx)) * 32 + (lcA[i] & 3) * 8,
                  As + PbA[i]);
    }
#pragma unroll
    for (int i = 0; i < 2; ++i)
      gload_lds16(wb2 + rowB[i] * 320 + kb * 64 + lcB[i] * 8, Bs + PbB[i]);
    __syncthreads();

    bf16x8 af[4][2], bfr[2][2];
#pragma unroll
    for (int mi = 0; mi < 4; ++mi)
#pragma unroll
      for (int kh = 0; kh < 2; ++kh) {
        int row = wm * 64 + mi * 16 + lr;
        int byte = row * 128 + ((kh * 64 + lg * 16) ^ ((row & 7) << 4));
        af[mi][kh] = *(const bf16x8*)(As + byte);
      }
#pragma unroll
    for (int ni = 0; ni < 2; ++ni)
#pragma unroll
      for (int kh = 0; kh < 2; ++kh) {
        int row = wn * 32 + ni * 16 + lr;
        int byte = row * 128 + ((kh * 64 + lg * 16) ^ ((row & 7) << 4));
        bfr[ni][kh] = *(const bf16x8*)(Bs + byte);
      }
#pragma unroll
    for (int mi = 0; mi < 4; ++mi)
#pragma unroll
      for (int ni = 0; ni < 2; ++ni)
#pragma unroll
        for (int kh = 0; kh < 2; ++kh)
          acc[mi][ni] = __builtin_amdgcn_mfma_f32_16x16x32_bf16(af[mi][kh], bfr[ni][kh],
                                                                acc[mi][ni], 0, 0, 0);
  }

  __syncthreads();
  if (tid < 128) bins[tid] = 0.f;
  __syncthreads();
  unsigned short* ob = x2 + (size_t)b * 1081600;
#pragma unroll
  for (int ni = 0; ni < 2; ++ni) {
    int oc = wn * 32 + ni * 16 + lr;
    float s = 0.f, q = 0.f;
#pragma unroll
    for (int mi = 0; mi < 4; ++mi)
#pragma unroll
      for (int r = 0; r < 4; ++r) {
        int m = wm * 64 + mi * 16 + lg * 4 + r;
        float v = acc[mi][ni][r];
        ob[((y + 1) * 130 + m + 1) * 64 + oc] = f2bfu(v);
        s += v; q += v * v;
      }
    atomicAdd(&bins[oc * 2], s);
    atomicAdd(&bins[oc * 2 + 1], q);
  }
  __syncthreads();
  if (tid < 128) atomicAdd(&st2[b * 128 + tid], bins[tid]);
}

// ---------------- conv3 MFMA: x2[8,130,130,64] -> x3[8,65,65,128] + stats ----------------
// BM=128 (2 out rows x 64), BN=128, 9 k-steps of K=64 (one tap).
__global__ __launch_bounds__(256) void conv3_k(const unsigned short* __restrict__ x2,
                                               const unsigned short* __restrict__ wb3,
                                               unsigned short* __restrict__ x3,
                                               float* __restrict__ st3) {
  __shared__ char smem[33792];
  char* As = smem;                       // [128][64]
  char* Bs = smem + 16384;               // [128][64]
  float* bins = (float*)(smem + 32768);  // [128][2]
  int tid = threadIdx.x, y0 = blockIdx.x * 2, b = blockIdx.y;
  int lane = tid & 63, w = tid >> 6, wm = w >> 1, wn = w & 1;
  int lr = lane & 15, lg = lane >> 4;
  f32x4 acc[4][4];
#pragma unroll
  for (int i = 0; i < 4; ++i)
#pragma unroll
    for (int j = 0; j < 4; ++j) acc[i][j] = (f32x4){0.f, 0.f, 0.f, 0.f};

  int rowS[4], lc[4], Pb[4];
#pragma unroll
  for (int i = 0; i < 4; ++i) {
    int pb = i * 256 + tid;
    Pb[i] = pb * 16; rowS[i] = pb >> 3; lc[i] = (pb & 7) ^ (rowS[i] & 7);
  }
  const unsigned short* xb = x2 + (size_t)b * 1081600;

  for (int kk = 0; kk < 9; ++kk) {
    int ky = kk / 3, kx = kk % 3;
    __syncthreads();
#pragma unroll
    for (int i = 0; i < 4; ++i) {
      int m = rowS[i], di = m >> 6, xx = m & 63;
      gload_lds16(xb + ((size_t)((2 * (y0 + di) + ky) * 130 + 2 * xx + kx)) * 64 + lc[i] * 8,
                  As + Pb[i]);
    }
#pragma unroll
    for (int i = 0; i < 4; ++i)
      gload_lds16(wb3 + (rowS[i] * 9 + kk) * 64 + lc[i] * 8, Bs + Pb[i]);
    __syncthreads();

    bf16x8 af[4][2], bfr[4][2];
#pragma unroll
    for (int mi = 0; mi < 4; ++mi)
#pragma unroll
      for (int kh = 0; kh < 2; ++kh) {
        int row = wm * 64 + mi * 16 + lr;
        int byte = row * 128 + ((kh * 64 + lg * 16) ^ ((row & 7) << 4));
        af[mi][kh] = *(const bf16x8*)(As + byte);
      }
#pragma unroll
    for (int ni = 0; ni < 4; ++ni)
#pragma unroll
      for (int kh = 0; kh < 2; ++kh) {
        int row = wn * 64 + ni * 16 + lr;
        int byte = row * 128 + ((kh * 64 + lg * 16) ^ ((row & 7) << 4));
        bfr[ni][kh] = *(const bf16x8*)(Bs + byte);
      }
#pragma unroll
    for (int mi = 0; mi < 4; ++mi)
#pragma unroll
      for (int ni = 0; ni < 4; ++ni)
#pragma unroll
        for (int kh = 0; kh < 2; ++kh)
          acc[mi][ni] = __builtin_amdgcn_mfma_f32_16x16x32_bf16(af[mi][kh], bfr[ni][kh],
                                                                acc[mi][ni], 0, 0, 0);
  }

  __syncthreads();
  if (tid < 256) bins[tid] = 0.f;
  __syncthreads();
  unsigned short* ob = x3 + (size_t)b * 540800;
#pragma unroll
  for (int ni = 0; ni < 4; ++ni) {
    int oc = wn * 64 + ni * 16 + lr;
    float s = 0.f, q = 0.f;
#pragma unroll
    for (int mi = 0; mi < 4; ++mi)
#pragma unroll
      for (int r = 0; r < 4; ++r) {
        int m = wm * 64 + mi * 16 + lg * 4 + r;
        int di = m >> 6, xx = m & 63;
        float v = acc[mi][ni][r];
        ob[((y0 + di) * 65 + xx) * 128 + oc] = f2bfu(v);
        s += v; q += v * v;
      }
    atomicAdd(&bins[oc * 2], s);
    atomicAdd(&bins[oc * 2 + 1], q);
  }
  __syncthreads();
  if (tid < 256) atomicAdd(&st3[b * 256 + tid], bins[tid]);
}

// ---------------- convT MFMA (unified): x3[8,65,65,128] -> y4[8,128,128,256] + stats ----------
// A-row = 4-neighbor concat (K=512); N = class*256+oc (1024). BM=128 (2 i-rows x 64 j), BN=128.
__global__ __launch_bounds__(256) void convT_k(const unsigned short* __restrict__ x3,
                                               const unsigned short* __restrict__ wbt,
                                               unsigned short* __restrict__ y4,
                                               float* __restrict__ st4) {
  __shared__ char smem[33792];
  char* As = smem;
  char* Bs = smem + 16384;
  float* bins = (float*)(smem + 32768);
  int tid = threadIdx.x, i0 = blockIdx.x * 2, nblk = blockIdx.y, b = blockIdx.z;
  int n0 = nblk * 128, cl = nblk >> 1, och0 = (nblk & 1) * 128;
  int lane = tid & 63, w = tid >> 6, wm = w >> 1, wn = w & 1;
  int lr = lane & 15, lg = lane >> 4;
  f32x4 acc[4][4];
#pragma unroll
  for (int i = 0; i < 4; ++i)
#pragma unroll
    for (int j = 0; j < 4; ++j) acc[i][j] = (f32x4){0.f, 0.f, 0.f, 0.f};

  int rowS[4], lc[4], Pb[4];
#pragma unroll
  for (int i = 0; i < 4; ++i) {
    int pb = i * 256 + tid;
    Pb[i] = pb * 16; rowS[i] = pb >> 3; lc[i] = (pb & 7) ^ (rowS[i] & 7);
  }
  const unsigned short* xb = x3 + (size_t)b * 540800;

  for (int kb = 0; kb < 8; ++kb) {
    int nb = kb >> 1, chalf = (kb & 1) * 64;
    __syncthreads();
#pragma unroll
    for (int i = 0; i < 4; ++i) {
      int m = rowS[i], di = m >> 6, j = m & 63;
      int pi = i0 + di + (nb >> 1), pj = j + (nb & 1);
      gload_lds16(xb + ((size_t)(pi * 65 + pj)) * 128 + chalf + lc[i] * 8, As + Pb[i]);
    }
#pragma unroll
    for (int i = 0; i < 4; ++i)
      gload_lds16(wbt + (size_t)(n0 + rowS[i]) * 512 + kb * 64 + lc[i] * 8, Bs + Pb[i]);
    __syncthreads();

    bf16x8 af[4][2], bfr[4][2];
#pragma unroll
    for (int mi = 0; mi < 4; ++mi)
#pragma unroll
      for (int kh = 0; kh < 2; ++kh) {
        int row = wm * 64 + mi * 16 + lr;
        int byte = row * 128 + ((kh * 64 + lg * 16) ^ ((row & 7) << 4));
        af[mi][kh] = *(const bf16x8*)(As + byte);
      }
#pragma unroll
    for (int ni = 0; ni < 4; ++ni)
#pragma unroll
      for (int kh = 0; kh < 2; ++kh) {
        int row = wn * 64 + ni * 16 + lr;
        int byte = row * 128 + ((kh * 64 + lg * 16) ^ ((row & 7) << 4));
        bfr[ni][kh] = *(const bf16x8*)(Bs + byte);
      }
#pragma unroll
    for (int mi = 0; mi < 4; ++mi)
#pragma unroll
      for (int ni = 0; ni < 4; ++ni)
#pragma unroll
        for (int kh = 0; kh < 2; ++kh)
          acc[mi][ni] = __builtin_amdgcn_mfma_f32_16x16x32_bf16(af[mi][kh], bfr[ni][kh],
                                                                acc[mi][ni], 0, 0, 0);
  }

  __syncthreads();
  if (tid < 256) bins[tid] = 0.f;
  __syncthreads();
  unsigned short* ob = y4 + (size_t)b * 4194304;
  int dy = cl >> 1, dx = cl & 1;
#pragma unroll
  for (int ni = 0; ni < 4; ++ni) {
    int loc = wn * 64 + ni * 16 + lr;
    int oc = och0 + loc;
    float s = 0.f, q = 0.f;
#pragma unroll
    for (int mi = 0; mi < 4; ++mi)
#pragma unroll
      for (int r = 0; r < 4; ++r) {
        int m = wm * 64 + mi * 16 + lg * 4 + r;
        int di = m >> 6, j = m & 63;
        int oy = 2 * (i0 + di) + dy, ox = 2 * j + dx;
        float v = acc[mi][ni][r];
        ob[(oy * 128 + ox) * 256 + oc] = f2bfu(v);
        s += v; q += v * v;
      }
    atomicAdd(&bins[loc * 2], s);
    atomicAdd(&bins[loc * 2 + 1], q);
  }
  __syncthreads();
  if (tid < 256) atomicAdd(&st4[b * 512 + och0 * 2 + tid], bins[tid]);
}

// ---------------- label map + counts ----------------
__global__ void lab_k(const float* __restrict__ seg, int* __restrict__ lab,
                      float* __restrict__ counts) {
  __shared__ int hist[19];
  int t = threadIdx.x;
  if (t < 19) hist[t] = 0;
  __syncthreads();
  int b = blockIdx.y;
  int p = blockIdx.x * 256 + t;
  int i = p >> 7, j = p & 127;
  const float* sp = seg + (size_t)b * 19 * 65536 + (2 * i) * 256 + 2 * j;
  int l = 0;
  for (int k = 0; k < 19; ++k) { if (sp[(size_t)k * 65536] != 0.f) { l = k; break; } }
  lab[b * 16384 + p] = l;
  atomicAdd(&hist[l], 1);
  __syncthreads();
  if (t < 19) atomicAdd(&counts[b * 19 + t], (float)hist[t]);
}

// ---------------- conv4 MFMA + bias + tanh + fused segment sums ----------------
__global__ __launch_bounds__(256) void conv4_k(
    const unsigned short* __restrict__ xq, const unsigned short* __restrict__ wb,
    const float* __restrict__ b4, const int* __restrict__ lab, float* __restrict__ sums) {
  __shared__ char smem[33280];
  char* As = smem;
  char* Bs = smem + 16384;
  int* labs = (int*)(smem + 32768);
  int tid = threadIdx.x;
  int y = blockIdx.x, nblk = blockIdx.y, b = blockIdx.z;
  int n0 = nblk * 128;
  if (tid < 128) labs[tid] = lab[b * 16384 + y * 128 + tid];
  int lane = tid & 63, w = tid >> 6;
  int wm = w >> 1, wn = w & 1;
  int lr = lane & 15, lg = lane >> 4;

  f32x4 acc[4][4];
#pragma unroll
  for (int a = 0; a < 4; ++a)
#pragma unroll
    for (int c = 0; c < 4; ++c) acc[a][c] = (f32x4){0.f, 0.f, 0.f, 0.f};

  const unsigned short* xb = xq + (size_t)b * (128 * 128 * 256);

  int rowS[4], icof[4], Pb[4];
#pragma unroll
  for (int i = 0; i < 4; ++i) {
    int pb = i * 256 + tid;
    Pb[i] = pb * 16;
    rowS[i] = pb >> 3;
    icof[i] = ((pb & 7) ^ (rowS[i] & 7)) << 3;
  }

  for (int kk = 0; kk < 9; ++kk) {
    int ky = kk / 3, kx = kk % 3;
    int sy = y + ky - 1; sy = sy < 0 ? 1 : (sy > 127 ? 126 : sy);
    for (int ic0 = 0; ic0 < 256; ic0 += 64) {
      __syncthreads();
#pragma unroll
      for (int i = 0; i < 4; ++i) {
        int m = rowS[i];
        int sx = m + kx - 1; sx = sx < 0 ? 1 : (sx > 127 ? 126 : sx);
        gload_lds16(xb + ((size_t)(sy * 128 + sx)) * 256 + ic0 + icof[i], As + Pb[i]);
      }
#pragma unroll
      for (int i = 0; i < 4; ++i) {
        int n = rowS[i];
        gload_lds16(wb + ((size_t)((n0 + n) * 9 + kk)) * 256 + ic0 + icof[i], Bs + Pb[i]);
      }
      __syncthreads();

      bf16x8 af[4][2], bfr[4][2];
#pragma unroll
      for (int mi = 0; mi < 4; ++mi)
#pragma unroll
        for (int kh = 0; kh < 2; ++kh) {
          int row = wm * 64 + mi * 16 + lr;
          int byte = (row << 7) + kh * 64 + lg * 16;
          byte ^= (row & 7) << 4;
          af[mi][kh] = *(const bf16x8*)(As + byte);
        }
#pragma unroll
      for (int ni = 0; ni < 4; ++ni)
#pragma unroll
        for (int kh = 0; kh < 2; ++kh) {
          int row = wn * 64 + ni * 16 + lr;
          int byte = (row << 7) + kh * 64 + lg * 16;
          byte ^= (row & 7) << 4;
          bfr[ni][kh] = *(const bf16x8*)(Bs + byte);
        }
#pragma unroll
      for (int mi = 0; mi < 4; ++mi)
#pragma unroll
        for (int ni = 0; ni < 4; ++ni)
#pragma unroll
          for (int kh = 0; kh < 2; ++kh)
            acc[mi][ni] = __builtin_amdgcn_mfma_f32_16x16x32_bf16(
                af[mi][kh], bfr[ni][kh], acc[mi][ni], 0, 0, 0);
    }
  }

  __syncthreads();
  float* bins = (float*)smem;  // [19][128]
  for (int t2 = tid; t2 < 19 * 128; t2 += 256) bins[t2] = 0.f;
  __syncthreads();
  float bias[4];
#pragma unroll
  for (int ni = 0; ni < 4; ++ni) bias[ni] = b4[n0 + wn * 64 + ni * 16 + lr];
#pragma unroll
  for (int mi = 0; mi < 4; ++mi)
#pragma unroll
    for (int ni = 0; ni < 4; ++ni) {
      int ct = wn * 64 + ni * 16 + lr;
#pragma unroll
      for (int r = 0; r < 4; ++r) {
        int x = wm * 64 + mi * 16 + lg * 4 + r;
        float v = tanhf(acc[mi][ni][r] + bias[ni]);
        atomicAdd(&bins[labs[x] * 128 + ct], v);
      }
    }
  __syncthreads();
  for (int t2 = tid; t2 < 19 * 128; t2 += 256) {
    float v = bins[t2];
    if (v != 0.f)
      atomicAdd(&sums[((size_t)(b * 19 + (t2 >> 7))) * 512 + n0 + (t2 & 127)], v);
  }
}

// ---------------- finalize ----------------
__global__ void finalize_k(const float* __restrict__ sums, const float* __restrict__ counts,
                           float* __restrict__ out) {
  int idx = blockIdx.x * 256 + threadIdx.x;
  int bl = idx / 512;
  float c = counts[bl];
  out[idx] = c > 0.f ? sums[idx] / fmaxf(c, 1.f) : 0.f;
}

extern "C" void kernel_launch(void* const* d_in, const int* in_sizes, int n_in,
                              void* d_out, int out_size, void* d_ws, size_t ws_size,
                              hipStream_t stream) {
  const float* image = (const float*)d_in[0];
  const float* seg   = (const float*)d_in[1];
  const float* w1    = (const float*)d_in[2];
  const float* w2    = (const float*)d_in[4];
  const float* w3    = (const float*)d_in[6];
  const float* wt    = (const float*)d_in[8];
  const float* w4    = (const float*)d_in[10];
  const float* b4    = (const float*)d_in[11];
  float* out = (float*)d_out;
  char* ws = (char*)d_ws;

  unsigned short* x1  = (unsigned short*)(ws + OFF_X1);
  unsigned short* x2  = (unsigned short*)(ws + OFF_X2);
  unsigned short* x3  = (unsigned short*)(ws + OFF_X3);
  unsigned short* y4  = (unsigned short*)(ws + OFF_Y4);
  unsigned short* wb4 = (unsigned short*)(ws + OFF_WB4);
  unsigned short* wb2 = (unsigned short*)(ws + OFF_WB2);
  unsigned short* wb3 = (unsigned short*)(ws + OFF_WB3);
  unsigned short* wbt = (unsigned short*)(ws + OFF_WBT);
  float* st1 = (float*)(ws + OFF_ST1);
  float* st2 = (float*)(ws + OFF_ST2);
  float* st3 = (float*)(ws + OFF_ST3);
  float* st4 = (float*)(ws + OFF_ST4);
  float* sums = (float*)(ws + OFF_SUMS);
  float* counts = (float*)(ws + OFF_CNT);
  float2* ms1 = (float2*)(ws + OFF_MS1);
  float2* ms2 = (float2*)(ws + OFF_MS2);
  float2* ms3 = (float2*)(ws + OFF_MS3);
  float2* ms4 = (float2*)(ws + OFF_MS4);
  int* lab = (int*)(ws + OFF_LAB);

  hipMemsetAsync(ws, 0, 60039168, stream);                 // x1,x2,x3 pads
  hipMemsetAsync(ws + OFF_ST1, 0, 342624, stream);         // stats+sums+counts

  // weight repacks + labels (independent)
  wrep2_k<<<80, 256, 0, stream>>>(w2, wb2);
  wrep3_k<<<288, 256, 0, stream>>>(w3, wb3);
  wrepT_k<<<2048, 256, 0, stream>>>(wt, wbt);
  wrep4_k<<<4608, 256, 0, stream>>>(w4, wb4);
  lab_k<<<dim3(64, 8), 256, 0, stream>>>(seg, lab, counts);

  // conv1 -> x1 (padded NHWC bf16), stats, norm
  conv1_k<<<dim3(256, 8), 256, 0, stream>>>(image, w1, x1);
  statsn_k<32><<<dim3(16, 8), 256, 0, stream>>>(x1 + 259 * 32, 258 * 32, 10, 16, 2130048L, st1);
  msn_k<<<1, 256, 0, stream>>>(st1, ms1, 1.f / 65536.f, 256);
  nln_k<32><<<dim3(256, 8), 256, 0, stream>>>(x1 + 259 * 32, 258 * 32, 1024, 2130048L, ms1);

  // conv2 -> x2 + stats, norm
  conv2_k<<<dim3(128, 8), 256, 0, stream>>>(x1, wb2, x2, st2);
  msn_k<<<2, 256, 0, stream>>>(st2, ms2, 1.f / 16384.f, 512);
  nln_k<64><<<dim3(128, 8), 256, 0, stream>>>(x2 + 131 * 64, 130 * 64, 1024, 1081600L, ms2);

  // conv3 -> x3 + stats, norm
  conv3_k<<<dim3(32, 8), 256, 0, stream>>>(x2, wb3, x3, st3);
  msn_k<<<4, 256, 0, stream>>>(st3, ms3, 1.f / 4096.f, 1024);
  nln_k<128><<<dim3(64, 8), 256, 0, stream>>>(x3, 65 * 128, 1024, 540800L, ms3);

  // convT -> y4 + stats, norm
  convT_k<<<dim3(32, 8, 8), 256, 0, stream>>>(x3, wbt, y4, st4);
  msn_k<<<8, 256, 0, stream>>>(st4, ms4, 1.f / 16384.f, 2048);
  nln_k<256><<<dim3(128, 8), 256, 0, stream>>>(y4, 128 * 256, 4096, 4194304L, ms4);

  // conv4 + fused epilogue
  conv4_k<<<dim3(128, 4, 8), 256, 0, stream>>>(y4, wb4, b4, lab, sums);

  finalize_k<<<304, 256, 0, stream>>>(sums, counts, out);
}